// Round 1
// baseline (1835.748 us; speedup 1.0000x reference)
//
#include <hip/hip_runtime.h>

#define B_ 32
#define C_ 384
#define TX_ 512
#define TY_ 2048
#define KW_ 3
#define EPS_ 1e-5f

typedef __attribute__((ext_vector_type(8))) short short8;
typedef __attribute__((ext_vector_type(4))) float f32x4;

#define MFMA(a, b, c) __builtin_amdgcn_mfma_f32_16x16x32_bf16(a, b, c, 0, 0, 0)

__device__ inline unsigned short f2bf(float f) {
    union { float f; unsigned int u; } v; v.f = f;
    unsigned int r = v.u + 0x7fffu + ((v.u >> 16) & 1u);
    return (unsigned short)(r >> 16);
}
__device__ inline float bf2f(unsigned short s) {
    union { float f; unsigned int u; } v; v.u = ((unsigned int)s) << 16;
    return v.f;
}

template<bool INBF>
__device__ inline float ldx(const void* p, size_t i) {
    if constexpr (INBF) return bf2f(((const unsigned short*)p)[i]);
    else return ((const float*)p)[i];
}

// ---- pack conv weights f32 [NL][O][I][K] -> bf16 [pred][layer][o][k*C+i]
__global__ __launch_bounds__(256) void pack_w(const float* cw0, const float* cw1,
                                              const float* cw2, unsigned short* wp) {
    int idx = blockIdx.x * 256 + threadIdx.x;
    const int per = 2 * C_ * C_ * KW_;
    if (idx >= 3 * per) return;
    int p = idx / per, r = idx % per;
    int l = r / (C_ * C_ * KW_), r2 = r % (C_ * C_ * KW_);
    int o = r2 / (C_ * KW_), kap = r2 % (C_ * KW_);
    int k = kap / C_, i = kap % C_;
    const float* cw = (p == 0) ? cw0 : (p == 1) ? cw1 : cw2;
    wp[idx] = f2bf(cw[((size_t)(l * C_ + o) * C_ + i) * KW_ + k]);
}

// ---- f32 -> bf16 (vectorized)
__global__ __launch_bounds__(256) void cvt_bf4(const float4* x, ushort4* o, int n4) {
    int i = blockIdx.x * 256 + threadIdx.x;
    if (i < n4) {
        float4 v = x[i];
        ushort4 r;
        r.x = f2bf(v.x); r.y = f2bf(v.y); r.z = f2bf(v.z); r.w = f2bf(v.w);
        o[i] = r;
    }
}

// ---- LN stats (mean, rstd) over C at each (b,t) of an f32 [B,C,T] tensor
__global__ __launch_bounds__(256) void ln_stats_f32(const float* x, float2* st, int T) {
    __shared__ float r1[4][64], r2[4][64];
    int b = blockIdx.y, t0 = blockIdx.x * 64;
    int tl = threadIdx.x & 63, g = threadIdx.x >> 6;
    int t = t0 + tl;
    const float* p = x + (size_t)b * C_ * T + t;
    float s = 0.f, ss = 0.f;
    for (int c = g; c < C_; c += 4) { float v = p[(size_t)c * T]; s += v; ss += v * v; }
    r1[g][tl] = s; r2[g][tl] = ss;
    __syncthreads();
    if (threadIdx.x < 64) {
        float s1 = r1[0][tl] + r1[1][tl] + r1[2][tl] + r1[3][tl];
        float s2 = r2[0][tl] + r2[1][tl] + r2[2][tl] + r2[3][tl];
        float m = s1 * (1.f / C_);
        float var = s2 * (1.f / C_) - m * m;
        st[(size_t)b * T + t0 + tl] = make_float2(m, rsqrtf(var + EPS_));
    }
}

// ---- fused LN -> conv1d(K=3) -> bias -> SiLU -> mask.
// !PRED: store H (bf16) + emit LN stats of H (for next layer).
//  PRED: fold 1x1 projection: pred[b,t] = (sum_o y[o,t]*ow[o] + ob) * mask.
template<bool INBF, bool PRED>
__global__ __launch_bounds__(256) void conv_ln(
    const void* __restrict__ Xin, const float2* __restrict__ stin,
    const float* __restrict__ g, const float* __restrict__ bet,
    const unsigned short* __restrict__ Wl, const float* __restrict__ cb,
    const float* __restrict__ mask,
    unsigned short* __restrict__ Hout, float2* __restrict__ stout,
    float* __restrict__ pred, const float* __restrict__ ow,
    const float* __restrict__ obias, int T)
{
    __shared__ __align__(16) unsigned short xs[66 * 384];
    const int tid = threadIdx.x;
    const int b = blockIdx.y;
    const int t0 = blockIdx.x * 64;
    const int lane = tid & 63;
    const int wave = tid >> 6;
    const int lr = lane & 15, lg = lane >> 4;
    const int wm = (wave >> 1) * 192, wn = (wave & 1) * 32;

    // stage LN(X) tile: LDS rows tt=0..65 <-> t = t0-1+tt, 384 bf16/row, XOR-swizzled 16B granules
    {
        const int tt = 1 + lane;
        const int t = t0 + lane;
        const float2 mr = stin[(size_t)b * T + t];
        for (int cg = wave; cg < 48; cg += 4) {
            const size_t base = ((size_t)b * C_ + cg * 8) * T + t;
            short8 v8;
            #pragma unroll
            for (int j = 0; j < 8; j++) {
                float v = ldx<INBF>(Xin, base + (size_t)j * T);
                float xn = (v - mr.x) * mr.y * g[cg * 8 + j] + bet[cg * 8 + j];
                v8[j] = (short)f2bf(xn);
            }
            const int ph = (cg & ~7) | ((cg ^ tt) & 7);
            *(short8*)&xs[tt * 384 + ph * 8] = v8;
        }
        if (tid < 96) {  // halo rows (zero-padded SAME conv)
            const int tt2 = (tid < 48) ? 0 : 65;
            const int cg = tid % 48;
            const int t2 = t0 - 1 + tt2;
            short8 v8;
            if (t2 >= 0 && t2 < T) {
                const float2 mr2 = stin[(size_t)b * T + t2];
                const size_t base = ((size_t)b * C_ + cg * 8) * T + t2;
                #pragma unroll
                for (int j = 0; j < 8; j++) {
                    float v = ldx<INBF>(Xin, base + (size_t)j * T);
                    float xn = (v - mr2.x) * mr2.y * g[cg * 8 + j] + bet[cg * 8 + j];
                    v8[j] = (short)f2bf(xn);
                }
            } else {
                #pragma unroll
                for (int j = 0; j < 8; j++) v8[j] = 0;
            }
            const int ph = (cg & ~7) | ((cg ^ tt2) & 7);
            *(short8*)&xs[tt2 * 384 + ph * 8] = v8;
        }
    }
    __syncthreads();

    // K-loop: Y[o,t] = sum_k sum_i W[o][k*384+i] * Xhat[i][t+k-1]
    f32x4 acc[12][2];
    const f32x4 zero = {0.f, 0.f, 0.f, 0.f};
    #pragma unroll
    for (int fm = 0; fm < 12; fm++) { acc[fm][0] = zero; acc[fm][1] = zero; }

    for (int k = 0; k < KW_; k++) {
        for (int ib = 0; ib < 12; ib++) {
            short8 bf0, bf1;
            {
                const int cgi = ib * 4 + lg;
                const int row0 = k + wn + lr;
                const int ph0 = (cgi & ~7) | ((cgi ^ row0) & 7);
                bf0 = *(const short8*)&xs[row0 * 384 + ph0 * 8];
                const int row1 = row0 + 16;
                const int ph1 = (cgi & ~7) | ((cgi ^ row1) & 7);
                bf1 = *(const short8*)&xs[row1 * 384 + ph1 * 8];
            }
            const int kap = k * 384 + ib * 32 + lg * 8;
            #pragma unroll
            for (int fm = 0; fm < 12; fm++) {
                const int o = wm + fm * 16 + lr;
                const short8 af = *(const short8*)&Wl[(size_t)o * 1152 + kap];
                acc[fm][0] = MFMA(af, bf0, acc[fm][0]);
                acc[fm][1] = MFMA(af, bf1, acc[fm][1]);
            }
        }
    }

    // epilogue
    __syncthreads();
    float* red = (float*)xs;
    if (tid < (PRED ? 64 : 128)) red[tid] = 0.f;
    __syncthreads();

    #pragma unroll
    for (int fn = 0; fn < 2; fn++) {
        const int tl = wn + fn * 16 + lr;
        const int t = t0 + tl;
        const float mk = mask[(size_t)b * T + t];
        float s1 = 0.f, s2 = 0.f;
        #pragma unroll
        for (int fm = 0; fm < 12; fm++) {
            const int o0 = wm + fm * 16 + lg * 4;
            #pragma unroll
            for (int j = 0; j < 4; j++) {
                const float h = acc[fm][fn][j] + cb[o0 + j];
                const float y = h * (1.f / (1.f + __expf(-h))) * mk;
                if constexpr (!PRED) {
                    Hout[((size_t)b * C_ + o0 + j) * T + t] = f2bf(y);
                    s1 += y; s2 += y * y;
                } else {
                    s1 += y * ow[o0 + j];
                }
            }
        }
        if constexpr (!PRED) {
            atomicAdd(&red[tl * 2], s1);
            atomicAdd(&red[tl * 2 + 1], s2);
        } else {
            atomicAdd(&red[tl], s1);
        }
    }
    __syncthreads();
    if (tid < 64) {
        const int t = t0 + tid;
        if constexpr (!PRED) {
            const float s1 = red[tid * 2], s2 = red[tid * 2 + 1];
            const float m = s1 * (1.f / C_);
            const float var = s2 * (1.f / C_) - m * m;
            stout[(size_t)b * T + t] = make_float2(m, rsqrtf(var + EPS_));
        } else {
            const float mk = mask[(size_t)b * T + t];
            pred[(size_t)b * T + t] = (red[tid] + obias[0]) * mk;
        }
    }
}

// ---- xe[b,c,y] = sum_t x[b,c,t] * path[b,t,y]; also LN stats of xe
__global__ __launch_bounds__(256) void bmm_ln(const unsigned short* __restrict__ xbf,
                                              const float* __restrict__ path,
                                              float* __restrict__ xe,
                                              float2* __restrict__ stout)
{
    __shared__ __align__(16) unsigned short ps[64 * 256];
    const int tid = threadIdx.x;
    const int b = blockIdx.y;
    const int y0 = blockIdx.x * 64;
    const int lane = tid & 63;
    const int wave = tid >> 6;
    const int lr = lane & 15, lg = lane >> 4;
    const int wm = (wave >> 1) * 192, wn = (wave & 1) * 32;

    f32x4 acc[12][2];
    const f32x4 zero = {0.f, 0.f, 0.f, 0.f};
    #pragma unroll
    for (int fm = 0; fm < 12; fm++) { acc[fm][0] = zero; acc[fm][1] = zero; }

    for (int kc = 0; kc < TX_; kc += 256) {
        __syncthreads();
        // stage path chunk [256 t x 64 y] -> LDS rows y, cols t (bf16, swizzled)
        for (int cg = wave; cg < 32; cg += 4) {
            const int yy = lane;
            const float* pp = path + ((size_t)b * TX_ + kc + cg * 8) * TY_ + (y0 + yy);
            short8 v8;
            #pragma unroll
            for (int j = 0; j < 8; j++) v8[j] = (short)f2bf(pp[(size_t)j * TY_]);
            const int ph = (cg & ~7) | ((cg ^ yy) & 7);
            *(short8*)&ps[yy * 256 + ph * 8] = v8;
        }
        __syncthreads();
        for (int ib = 0; ib < 8; ib++) {
            short8 bf0, bf1;
            {
                const int cgi = ib * 4 + lg;
                const int row0 = wn + lr;
                const int ph0 = (cgi & ~7) | ((cgi ^ row0) & 7);
                bf0 = *(const short8*)&ps[row0 * 256 + ph0 * 8];
                const int row1 = row0 + 16;
                const int ph1 = (cgi & ~7) | ((cgi ^ row1) & 7);
                bf1 = *(const short8*)&ps[row1 * 256 + ph1 * 8];
            }
            const int koff = kc + ib * 32 + lg * 8;
            #pragma unroll
            for (int fm = 0; fm < 12; fm++) {
                const int c = wm + fm * 16 + lr;
                const short8 af = *(const short8*)&xbf[((size_t)b * C_ + c) * TX_ + koff];
                acc[fm][0] = MFMA(af, bf0, acc[fm][0]);
                acc[fm][1] = MFMA(af, bf1, acc[fm][1]);
            }
        }
    }

    __syncthreads();
    float* red = (float*)ps;
    if (tid < 128) red[tid] = 0.f;
    __syncthreads();

    #pragma unroll
    for (int fn = 0; fn < 2; fn++) {
        const int yl = wn + fn * 16 + lr;
        const int y = y0 + yl;
        float s1 = 0.f, s2 = 0.f;
        #pragma unroll
        for (int fm = 0; fm < 12; fm++) {
            const int c0 = wm + fm * 16 + lg * 4;
            #pragma unroll
            for (int j = 0; j < 4; j++) {
                const float v = acc[fm][fn][j];
                xe[((size_t)b * C_ + c0 + j) * TY_ + y] = v;
                s1 += v; s2 += v * v;
            }
        }
        atomicAdd(&red[yl * 2], s1);
        atomicAdd(&red[yl * 2 + 1], s2);
    }
    __syncthreads();
    if (tid < 64) {
        const int y = y0 + tid;
        const float s1 = red[tid * 2], s2 = red[tid * 2 + 1];
        const float m = s1 * (1.f / C_);
        const float var = s2 * (1.f / C_) - m * m;
        stout[(size_t)b * TY_ + y] = make_float2(m, rsqrtf(var + EPS_));
    }
}

// ---- out = xe(in place) + pitch + energy
__global__ __launch_bounds__(256) void add3(float4* o, const float4* p, const float4* e, int n4) {
    for (int i = blockIdx.x * 256 + threadIdx.x; i < n4; i += gridDim.x * 256) {
        float4 a = o[i], x1 = p[i], x2 = e[i];
        a.x += x1.x + x2.x; a.y += x1.y + x2.y;
        a.z += x1.z + x2.z; a.w += x1.w + x2.w;
        o[i] = a;
    }
}

extern "C" void kernel_launch(void* const* d_in, const int* in_sizes, int n_in,
                              void* d_out, int out_size, void* d_ws, size_t ws_size,
                              hipStream_t stream)
{
    const float* x      = (const float*)d_in[0];
    const float* x_mask = (const float*)d_in[1];
    const float* y_mask = (const float*)d_in[2];
    const float* pitch  = (const float*)d_in[3];
    const float* energy = (const float*)d_in[4];
    const float* path   = (const float*)d_in[5];
    const float* prm[3][6];  // [dur,pit,ene] x [lng,lnb,cw,cb,ow,ob]
    for (int p = 0; p < 3; p++)
        for (int q = 0; q < 6; q++)
            prm[p][q] = (const float*)d_in[6 + p * 6 + q];

    float* out         = (float*)d_out;                 // chunk0 doubles as xe
    float* dur_pred    = out + (size_t)B_ * C_ * TY_;
    float* pitch_pred  = dur_pred + B_ * TX_;
    float* energy_pred = pitch_pred + B_ * TY_;

    const size_t LSZ = (size_t)C_ * C_ * KW_;           // 442368 per layer
    char* w = (char*)d_ws;
    unsigned short* Wp  = (unsigned short*)w; w += 3 * 2 * LSZ * 2;
    unsigned short* xbf = (unsigned short*)w; w += (size_t)B_ * C_ * TX_ * 2;
    unsigned short* H1  = (unsigned short*)w; w += (size_t)B_ * C_ * TY_ * 2;
    float2* st0 = (float2*)w; w += (size_t)B_ * TY_ * sizeof(float2);
    float2* st1 = (float2*)w; w += (size_t)B_ * TY_ * sizeof(float2);
    if ((size_t)(w - (char*)d_ws) > ws_size) return;    // ws too small: fail loudly

    pack_w<<<dim3((3 * 2 * (int)LSZ + 255) / 256), 256, 0, stream>>>(prm[0][2], prm[1][2], prm[2][2], Wp);
    cvt_bf4<<<dim3(B_ * C_ * TX_ / 4 / 256), 256, 0, stream>>>((const float4*)x, (ushort4*)xbf, B_ * C_ * TX_ / 4);
    ln_stats_f32<<<dim3(TX_ / 64, B_), 256, 0, stream>>>(x, st0, TX_);

    // duration predictor (T = TX, input x)
    conv_ln<false, false><<<dim3(TX_ / 64, B_), 256, 0, stream>>>(
        x, st0, prm[0][0], prm[0][1], Wp, prm[0][3], x_mask, H1, st1, nullptr, nullptr, nullptr, TX_);
    conv_ln<true, true><<<dim3(TX_ / 64, B_), 256, 0, stream>>>(
        H1, st1, prm[0][0] + C_, prm[0][1] + C_, Wp + LSZ, prm[0][3] + C_, x_mask,
        nullptr, nullptr, dur_pred, prm[0][4], prm[0][5], TX_);

    // length regulator: xe = x @ path -> out chunk0 (+ LN stats -> st0)
    bmm_ln<<<dim3(TY_ / 64, B_), 256, 0, stream>>>(xbf, path, out, st0);

    // pitch predictor (T = TY, input xe)
    conv_ln<false, false><<<dim3(TY_ / 64, B_), 256, 0, stream>>>(
        out, st0, prm[1][0], prm[1][1], Wp + 2 * LSZ, prm[1][3], y_mask, H1, st1, nullptr, nullptr, nullptr, TY_);
    conv_ln<true, true><<<dim3(TY_ / 64, B_), 256, 0, stream>>>(
        H1, st1, prm[1][0] + C_, prm[1][1] + C_, Wp + 3 * LSZ, prm[1][3] + C_, y_mask,
        nullptr, nullptr, pitch_pred, prm[1][4], prm[1][5], TY_);

    // energy predictor (T = TY, input xe; reuses st0)
    conv_ln<false, false><<<dim3(TY_ / 64, B_), 256, 0, stream>>>(
        out, st0, prm[2][0], prm[2][1], Wp + 4 * LSZ, prm[2][3], y_mask, H1, st1, nullptr, nullptr, nullptr, TY_);
    conv_ln<true, true><<<dim3(TY_ / 64, B_), 256, 0, stream>>>(
        H1, st1, prm[2][0] + C_, prm[2][1] + C_, Wp + 5 * LSZ, prm[2][3] + C_, y_mask,
        nullptr, nullptr, energy_pred, prm[2][4], prm[2][5], TY_);

    add3<<<dim3(2048), 256, 0, stream>>>((float4*)out, (const float4*)pitch, (const float4*)energy, B_ * C_ * TY_ / 4);
}

// Round 2
// 937.942 us; speedup vs baseline: 1.9572x; 1.9572x over previous
//
#include <hip/hip_runtime.h>

#define B_ 32
#define C_ 384
#define TX_ 512
#define TY_ 2048
#define KW_ 3
#define EPS_ 1e-5f

typedef __attribute__((ext_vector_type(8))) short short8;
typedef __attribute__((ext_vector_type(4))) float f32x4;

#define MFMA(a, b, c) __builtin_amdgcn_mfma_f32_16x16x32_bf16(a, b, c, 0, 0, 0)

__device__ inline unsigned short f2bf(float f) {
    union { float f; unsigned int u; } v; v.f = f;
    unsigned int r = v.u + 0x7fffu + ((v.u >> 16) & 1u);
    return (unsigned short)(r >> 16);
}
__device__ inline float bf2f(unsigned short s) {
    union { float f; unsigned int u; } v; v.u = ((unsigned int)s) << 16;
    return v.f;
}

template<bool INBF>
__device__ inline float ldx(const void* p, size_t i) {
    if constexpr (INBF) return bf2f(((const unsigned short*)p)[i]);
    else return ((const float*)p)[i];
}

// ---- pack conv weights f32 [NL][O][I][K] -> fragment-linear bf16:
// granule G = ((lay*36 + c)*384 + o)*4 + lg, c = k*12+ib; elements e=0..7 are
// W[o][i = ib*32 + lg*8 + e][k].  A wave's af read = contiguous 1KB.
__global__ __launch_bounds__(256) void pack_w2(const float* cw0, const float* cw1,
                                               const float* cw2, unsigned short* wp) {
    int idx = blockIdx.x * 256 + threadIdx.x;
    const int NG = 6 * 36 * 384 * 4;
    if (idx >= NG) return;
    int lg = idx & 3;
    int o = (idx >> 2) % 384;
    int c = ((idx >> 2) / 384) % 36;
    int lay = (idx >> 2) / (384 * 36);
    int k = c / 12, ib = c % 12;
    int pr = lay >> 1, l = lay & 1;
    const float* cw = ((pr == 0) ? cw0 : (pr == 1) ? cw1 : cw2) + (size_t)l * C_ * C_ * KW_;
    const float* src = cw + ((size_t)o * C_ + ib * 32 + lg * 8) * KW_ + k;
    short8 v;
    #pragma unroll
    for (int e = 0; e < 8; e++) v[e] = (short)f2bf(src[e * KW_]);
    *(short8*)&wp[(size_t)idx * 8] = v;
}

// ---- pack x f32 [B][C][TX] -> fragment-linear bf16 for bmm A-operand:
// granule G = ((b*16 + q)*384 + c)*4 + lg; elements e: x[b][c][q*32 + lg*8 + e]
__global__ __launch_bounds__(256) void pack_x2(const float* x, unsigned short* xp) {
    int idx = blockIdx.x * 256 + threadIdx.x;
    const int NG = B_ * 16 * 384 * 4;
    if (idx >= NG) return;
    int lg = idx & 3;
    int c = (idx >> 2) % 384;
    int q = ((idx >> 2) / 384) % 16;
    int b = (idx >> 2) / (384 * 16);
    const float* src = x + ((size_t)b * C_ + c) * TX_ + q * 32 + lg * 8;
    short8 v;
    #pragma unroll
    for (int e = 0; e < 8; e++) v[e] = (short)f2bf(src[e]);
    *(short8*)&xp[(size_t)idx * 8] = v;
}

// ---- LN stats (mean, rstd) over C at each (b,t) of f32 [B,C,T]
__global__ __launch_bounds__(256) void ln_stats_f32(const float* x, float2* st, int T) {
    __shared__ float r1[4][64], r2[4][64];
    int b = blockIdx.y, t0 = blockIdx.x * 64;
    int tl = threadIdx.x & 63, g = threadIdx.x >> 6;
    int t = t0 + tl;
    const float* p = x + (size_t)b * C_ * T + t;
    float s = 0.f, ss = 0.f;
    for (int c = g; c < C_; c += 4) { float v = p[(size_t)c * T]; s += v; ss += v * v; }
    r1[g][tl] = s; r2[g][tl] = ss;
    __syncthreads();
    if (threadIdx.x < 64) {
        float s1 = r1[0][tl] + r1[1][tl] + r1[2][tl] + r1[3][tl];
        float s2 = r2[0][tl] + r2[1][tl] + r2[2][tl] + r2[3][tl];
        float m = s1 * (1.f / C_);
        float var = s2 * (1.f / C_) - m * m;
        st[(size_t)b * T + t0 + tl] = make_float2(m, rsqrtf(var + EPS_));
    }
}

// ---- fused LN -> conv1d(K=3) -> bias -> SiLU -> mask, software-pipelined.
// Wave owns 96 o x 64 t (fm=6, fn=4); af double-buffered from L2 (fragment-
// packed W2), bf double-buffered from LDS.
template<bool INBF, bool PRED>
__global__ __launch_bounds__(256, 2) void conv_ln(
    const void* __restrict__ Xin, const float2* __restrict__ stin,
    const float* __restrict__ g, const float* __restrict__ bet,
    const unsigned short* __restrict__ W2, const float* __restrict__ cb,
    const float* __restrict__ mask,
    unsigned short* __restrict__ Hout, float2* __restrict__ stout,
    float* __restrict__ pred, const float* __restrict__ ow,
    const float* __restrict__ obias, int T)
{
    __shared__ __align__(16) unsigned short xs[66 * 384];
    const int tid = threadIdx.x;
    const int b = blockIdx.y;
    const int t0 = blockIdx.x * 64;
    const int lane = tid & 63;
    const int wave = tid >> 6;
    const int lr = lane & 15, lg = lane >> 4;
    const int wm = wave * 96;

    // ---- stage LN(X) tile: rows tt=0..65 <-> t = t0-1+tt, swizzled 16B granules
    {
        const int tt = 1 + lane;
        const int t = t0 + lane;
        const float2 mr = stin[(size_t)b * T + t];
        for (int cg = wave; cg < 48; cg += 4) {
            const size_t base = ((size_t)b * C_ + cg * 8) * T + t;
            short8 v8;
            #pragma unroll
            for (int j = 0; j < 8; j++) {
                float v = ldx<INBF>(Xin, base + (size_t)j * T);
                float xn = (v - mr.x) * mr.y * g[cg * 8 + j] + bet[cg * 8 + j];
                v8[j] = (short)f2bf(xn);
            }
            const int ph = (cg & ~7) | ((cg ^ tt) & 7);
            *(short8*)&xs[tt * 384 + ph * 8] = v8;
        }
        if (tid < 96) {  // halo rows (zero-padded SAME conv)
            const int tt2 = (tid < 48) ? 0 : 65;
            const int cg = tid % 48;
            const int t2 = t0 - 1 + tt2;
            short8 v8;
            if (t2 >= 0 && t2 < T) {
                const float2 mr2 = stin[(size_t)b * T + t2];
                const size_t base = ((size_t)b * C_ + cg * 8) * T + t2;
                #pragma unroll
                for (int j = 0; j < 8; j++) {
                    float v = ldx<INBF>(Xin, base + (size_t)j * T);
                    float xn = (v - mr2.x) * mr2.y * g[cg * 8 + j] + bet[cg * 8 + j];
                    v8[j] = (short)f2bf(xn);
                }
            } else {
                #pragma unroll
                for (int j = 0; j < 8; j++) v8[j] = 0;
            }
            const int ph = (cg & ~7) | ((cg ^ tt2) & 7);
            *(short8*)&xs[tt2 * 384 + ph * 8] = v8;
        }
    }
    __syncthreads();

    f32x4 acc[6][4];
    const f32x4 zero = {0.f, 0.f, 0.f, 0.f};
    #pragma unroll
    for (int fm = 0; fm < 6; fm++)
        #pragma unroll
        for (int fn = 0; fn < 4; fn++) acc[fm][fn] = zero;

    // per-lane af base: granule (c*384 + o)*4 + lg, o = wm + fm*16 + lr
    const unsigned short* wbase = W2 + (size_t)(wm * 4 + lr * 4 + lg) * 8;

    short8 afA[6], afB[6], bfA[4], bfB[4];

    auto LOADAF = [&](short8* dst, int c) {
        #pragma unroll
        for (int fm = 0; fm < 6; fm++)
            dst[fm] = *(const short8*)(wbase + (size_t)c * 12288 + fm * 512);
    };
    auto LOADBF = [&](short8* dst, int c) {
        const int k = c / 12, ib = c - k * 12;
        #pragma unroll
        for (int fn = 0; fn < 4; fn++) {
            const int row = k + fn * 16 + lr;
            const int cgi = ib * 4 + lg;
            const int ph = (cgi & ~7) | ((cgi ^ row) & 7);
            dst[fn] = *(const short8*)&xs[row * 384 + ph * 8];
        }
    };
    auto FMAS = [&](short8* af, short8* bf) {
        #pragma unroll
        for (int fm = 0; fm < 6; fm++)
            #pragma unroll
            for (int fn = 0; fn < 4; fn++)
                acc[fm][fn] = MFMA(af[fm], bf[fn], acc[fm][fn]);
    };

    LOADAF(afA, 0); LOADBF(bfA, 0);
    #pragma unroll
    for (int c = 0; c < 36; c += 2) {
        LOADAF(afB, c + 1); LOADBF(bfB, c + 1);
        FMAS(afA, bfA);
        const int c2 = (c + 2 < 36) ? c + 2 : 35;
        LOADAF(afA, c2); LOADBF(bfA, c2);
        FMAS(afB, bfB);
    }

    // ---- epilogue
    __syncthreads();
    float* red = (float*)xs;
    if (tid < (PRED ? 64 : 128)) red[tid] = 0.f;
    __syncthreads();

    #pragma unroll
    for (int fn = 0; fn < 4; fn++) {
        const int tl = fn * 16 + lr;
        const int t = t0 + tl;
        const float mk = mask[(size_t)b * T + t];
        float s1 = 0.f, s2 = 0.f;
        #pragma unroll
        for (int fm = 0; fm < 6; fm++) {
            const int o0 = wm + fm * 16 + lg * 4;
            #pragma unroll
            for (int j = 0; j < 4; j++) {
                const float h = acc[fm][fn][j] + cb[o0 + j];
                const float y = h * (1.f / (1.f + __expf(-h))) * mk;
                if constexpr (!PRED) {
                    Hout[((size_t)b * C_ + o0 + j) * T + t] = f2bf(y);
                    s1 += y; s2 += y * y;
                } else {
                    s1 += y * ow[o0 + j];
                }
            }
        }
        if constexpr (!PRED) {
            atomicAdd(&red[tl * 2], s1);
            atomicAdd(&red[tl * 2 + 1], s2);
        } else {
            atomicAdd(&red[tl], s1);
        }
    }
    __syncthreads();
    if (tid < 64) {
        const int t = t0 + tid;
        if constexpr (!PRED) {
            const float s1 = red[tid * 2], s2 = red[tid * 2 + 1];
            const float m = s1 * (1.f / C_);
            const float var = s2 * (1.f / C_) - m * m;
            stout[(size_t)b * T + t] = make_float2(m, rsqrtf(var + EPS_));
        } else {
            const float mk = mask[(size_t)b * T + t];
            pred[(size_t)b * T + t] = (red[tid] + obias[0]) * mk;
        }
    }
}

// ---- xe = x @ path; LN stats of xe; FUSED: out = xe+pitch+energy and xe->bf16
template<bool FUSED>
__global__ __launch_bounds__(256, 2) void bmm_ln(
    const unsigned short* __restrict__ x2, const float* __restrict__ path,
    const float* __restrict__ pitch, const float* __restrict__ energy,
    float* __restrict__ out, unsigned short* __restrict__ xebf,
    float2* __restrict__ stout)
{
    __shared__ __align__(16) unsigned short ps[64 * 256];
    const int tid = threadIdx.x;
    const int b = blockIdx.y;
    const int y0 = blockIdx.x * 64;
    const int lane = tid & 63;
    const int wave = tid >> 6;
    const int lr = lane & 15, lg = lane >> 4;
    const int wm = wave * 96;

    f32x4 acc[6][4];
    const f32x4 zero = {0.f, 0.f, 0.f, 0.f};
    #pragma unroll
    for (int fm = 0; fm < 6; fm++)
        #pragma unroll
        for (int fn = 0; fn < 4; fn++) acc[fm][fn] = zero;

    const unsigned short* xb = x2 + ((size_t)b * 16 * 1536 + wm * 4 + lr * 4 + lg) * 8;

    short8 afA[6], afB[6], bfA[4], bfB[4];

    auto LOADAF = [&](short8* dst, int q) {
        #pragma unroll
        for (int fm = 0; fm < 6; fm++)
            dst[fm] = *(const short8*)(xb + (size_t)q * 12288 + fm * 512);
    };
    auto LOADBF = [&](short8* dst, int u) {
        #pragma unroll
        for (int fn = 0; fn < 4; fn++) {
            const int row = fn * 16 + lr;
            const int cgi = u * 4 + lg;
            const int ph = (cgi & ~7) | ((cgi ^ row) & 7);
            dst[fn] = *(const short8*)&ps[row * 256 + ph * 8];
        }
    };
    auto FMAS = [&](short8* af, short8* bf) {
        #pragma unroll
        for (int fm = 0; fm < 6; fm++)
            #pragma unroll
            for (int fn = 0; fn < 4; fn++)
                acc[fm][fn] = MFMA(af[fm], bf[fn], acc[fm][fn]);
    };

    for (int s = 0; s < 2; s++) {
        __syncthreads();
        // stage path chunk [256 t x 64 y] -> rows y, bf16, swizzled
        for (int cg = wave; cg < 32; cg += 4) {
            const int yy = lane;
            const float* pp = path + ((size_t)b * TX_ + s * 256 + cg * 8) * TY_ + (y0 + yy);
            short8 v8;
            #pragma unroll
            for (int j = 0; j < 8; j++) v8[j] = (short)f2bf(pp[(size_t)j * TY_]);
            const int ph = (cg & ~7) | ((cg ^ yy) & 7);
            *(short8*)&ps[yy * 256 + ph * 8] = v8;
        }
        __syncthreads();
        const int qb = s * 8;
        LOADAF(afA, qb); LOADBF(bfA, 0);
        #pragma unroll
        for (int u = 0; u < 8; u += 2) {
            LOADAF(afB, qb + u + 1); LOADBF(bfB, u + 1);
            FMAS(afA, bfA);
            const int u2 = (u + 2 < 8) ? u + 2 : 7;
            LOADAF(afA, qb + u2); LOADBF(bfA, u2);
            FMAS(afB, bfB);
        }
    }

    // ---- epilogue
    __syncthreads();
    float* red = (float*)ps;
    if (tid < 128) red[tid] = 0.f;
    __syncthreads();

    #pragma unroll
    for (int fn = 0; fn < 4; fn++) {
        const int yl = fn * 16 + lr;
        const int y = y0 + yl;
        float s1 = 0.f, s2 = 0.f;
        #pragma unroll
        for (int fm = 0; fm < 6; fm++) {
            #pragma unroll
            for (int j = 0; j < 4; j++) {
                const int c = wm + fm * 16 + lg * 4 + j;
                const size_t gi = ((size_t)b * C_ + c) * TY_ + y;
                const float v = acc[fm][fn][j];
                if constexpr (FUSED) {
                    out[gi] = v + pitch[gi] + energy[gi];
                    xebf[gi] = f2bf(v);
                } else {
                    out[gi] = v;
                }
                s1 += v; s2 += v * v;
            }
        }
        atomicAdd(&red[yl * 2], s1);
        atomicAdd(&red[yl * 2 + 1], s2);
    }
    __syncthreads();
    if (tid < 64) {
        const int y = y0 + tid;
        const float s1 = red[tid * 2], s2 = red[tid * 2 + 1];
        const float m = s1 * (1.f / C_);
        const float var = s2 * (1.f / C_) - m * m;
        stout[(size_t)b * TY_ + y] = make_float2(m, rsqrtf(var + EPS_));
    }
}

// ---- out = xe(in place) + pitch + energy   (fallback only)
__global__ __launch_bounds__(256) void add3(float4* o, const float4* p, const float4* e, int n4) {
    for (int i = blockIdx.x * 256 + threadIdx.x; i < n4; i += gridDim.x * 256) {
        float4 a = o[i], x1 = p[i], x2 = e[i];
        a.x += x1.x + x2.x; a.y += x1.y + x2.y;
        a.z += x1.z + x2.z; a.w += x1.w + x2.w;
        o[i] = a;
    }
}

extern "C" void kernel_launch(void* const* d_in, const int* in_sizes, int n_in,
                              void* d_out, int out_size, void* d_ws, size_t ws_size,
                              hipStream_t stream)
{
    const float* x      = (const float*)d_in[0];
    const float* x_mask = (const float*)d_in[1];
    const float* y_mask = (const float*)d_in[2];
    const float* pitch  = (const float*)d_in[3];
    const float* energy = (const float*)d_in[4];
    const float* path   = (const float*)d_in[5];
    const float* prm[3][6];  // [dur,pit,ene] x [lng,lnb,cw,cb,ow,ob]
    for (int p = 0; p < 3; p++)
        for (int q = 0; q < 6; q++)
            prm[p][q] = (const float*)d_in[6 + p * 6 + q];

    float* out         = (float*)d_out;
    float* dur_pred    = out + (size_t)B_ * C_ * TY_;
    float* pitch_pred  = dur_pred + B_ * TX_;
    float* energy_pred = pitch_pred + B_ * TY_;

    const size_t LAY = (size_t)36 * 1536 * 8;            // 442368 shorts per layer
    char* w = (char*)d_ws;
    unsigned short* W2  = (unsigned short*)w; w += 6 * LAY * 2;
    unsigned short* x2p = (unsigned short*)w; w += (size_t)B_ * 16 * 1536 * 8 * 2;
    unsigned short* H1  = (unsigned short*)w; w += (size_t)B_ * C_ * TY_ * 2;
    float2* st0 = (float2*)w; w += (size_t)B_ * TY_ * sizeof(float2);
    float2* st1 = (float2*)w; w += (size_t)B_ * TY_ * sizeof(float2);
    unsigned short* xebf = (unsigned short*)w; w += (size_t)B_ * C_ * TY_ * 2;
    const bool fused = ((size_t)(w - (char*)d_ws) <= ws_size);

    pack_w2<<<dim3((6 * 36 * 384 * 4 + 255) / 256), 256, 0, stream>>>(prm[0][2], prm[1][2], prm[2][2], W2);
    pack_x2<<<dim3((B_ * 16 * 384 * 4 + 255) / 256), 256, 0, stream>>>(x, x2p);
    ln_stats_f32<<<dim3(TX_ / 64, B_), 256, 0, stream>>>(x, st0, TX_);

    // duration predictor (T = TX, input x f32)
    conv_ln<false, false><<<dim3(TX_ / 64, B_), 256, 0, stream>>>(
        x, st0, prm[0][0], prm[0][1], W2, prm[0][3], x_mask, H1, st1, nullptr, nullptr, nullptr, TX_);
    conv_ln<true, true><<<dim3(TX_ / 64, B_), 256, 0, stream>>>(
        H1, st1, prm[0][0] + C_, prm[0][1] + C_, W2 + LAY, prm[0][3] + C_, x_mask,
        nullptr, nullptr, dur_pred, prm[0][4], prm[0][5], TX_);

    if (fused) {
        bmm_ln<true><<<dim3(TY_ / 64, B_), 256, 0, stream>>>(x2p, path, pitch, energy, out, xebf, st0);

        conv_ln<true, false><<<dim3(TY_ / 64, B_), 256, 0, stream>>>(
            xebf, st0, prm[1][0], prm[1][1], W2 + 2 * LAY, prm[1][3], y_mask, H1, st1, nullptr, nullptr, nullptr, TY_);
        conv_ln<true, true><<<dim3(TY_ / 64, B_), 256, 0, stream>>>(
            H1, st1, prm[1][0] + C_, prm[1][1] + C_, W2 + 3 * LAY, prm[1][3] + C_, y_mask,
            nullptr, nullptr, pitch_pred, prm[1][4], prm[1][5], TY_);

        conv_ln<true, false><<<dim3(TY_ / 64, B_), 256, 0, stream>>>(
            xebf, st0, prm[2][0], prm[2][1], W2 + 4 * LAY, prm[2][3], y_mask, H1, st1, nullptr, nullptr, nullptr, TY_);
        conv_ln<true, true><<<dim3(TY_ / 64, B_), 256, 0, stream>>>(
            H1, st1, prm[2][0] + C_, prm[2][1] + C_, W2 + 5 * LAY, prm[2][3] + C_, y_mask,
            nullptr, nullptr, energy_pred, prm[2][4], prm[2][5], TY_);
    } else {
        bmm_ln<false><<<dim3(TY_ / 64, B_), 256, 0, stream>>>(x2p, path, nullptr, nullptr, out, nullptr, st0);

        conv_ln<false, false><<<dim3(TY_ / 64, B_), 256, 0, stream>>>(
            out, st0, prm[1][0], prm[1][1], W2 + 2 * LAY, prm[1][3], y_mask, H1, st1, nullptr, nullptr, nullptr, TY_);
        conv_ln<true, true><<<dim3(TY_ / 64, B_), 256, 0, stream>>>(
            H1, st1, prm[1][0] + C_, prm[1][1] + C_, W2 + 3 * LAY, prm[1][3] + C_, y_mask,
            nullptr, nullptr, pitch_pred, prm[1][4], prm[1][5], TY_);

        conv_ln<false, false><<<dim3(TY_ / 64, B_), 256, 0, stream>>>(
            out, st0, prm[2][0], prm[2][1], W2 + 4 * LAY, prm[2][3], y_mask, H1, st1, nullptr, nullptr, nullptr, TY_);
        conv_ln<true, true><<<dim3(TY_ / 64, B_), 256, 0, stream>>>(
            H1, st1, prm[2][0] + C_, prm[2][1] + C_, W2 + 5 * LAY, prm[2][3] + C_, y_mask,
            nullptr, nullptr, energy_pred, prm[2][4], prm[2][5], TY_);

        add3<<<dim3(2048), 256, 0, stream>>>((float4*)out, (const float4*)pitch, (const float4*)energy, B_ * C_ * TY_ / 4);
    }
}